// Round 15
// baseline (1523.953 us; speedup 1.0000x reference)
//
#include <hip/hip_runtime.h>
#include <math.h>

typedef __attribute__((ext_vector_type(8))) short bf16x8;
typedef __attribute__((ext_vector_type(4))) float f32x4;

#define PB 512    // persistent blocks: 2/CU x 256 CUs (co-resident even if half
                  // the machine is unavailable; 4/CU capacity per launch_bounds)

__device__ __forceinline__ float bfbits2f(unsigned short b){
  return __uint_as_float(((unsigned)b) << 16);
}
__device__ __forceinline__ unsigned short f2bfbits(float f){
  unsigned u = __float_as_uint(f);
  unsigned r = u + 0x7fffu + ((u >> 16) & 1u);
  return (unsigned short)(r >> 16);
}
__device__ __forceinline__ uint4 ld16(const void* __restrict__ base, unsigned byteoff){
  return *(const uint4*)((const char*)base + byteoff);
}
__device__ __forceinline__ uint2 ld8(const void* __restrict__ base, unsigned byteoff){
  return *(const uint2*)((const char*)base + byteoff);
}

// ================= Threefry-2x32 (JAX partitionable) =================
__host__ __device__ __forceinline__ unsigned rotl32(unsigned v, int d){
  return (v << d) | (v >> (32 - d));
}
__host__ __device__ __forceinline__ void tf2x32(unsigned k0, unsigned k1,
                                                unsigned c0, unsigned c1,
                                                unsigned &o0, unsigned &o1)
{
  unsigned ks2 = k0 ^ k1 ^ 0x1BD11BDAu;
  unsigned x0 = c0 + k0, x1 = c1 + k1;
#define TFR(r) x0 += x1; x1 = rotl32(x1, r); x1 ^= x0;
  TFR(13) TFR(15) TFR(26) TFR(6)
  x0 += k1;  x1 += ks2 + 1u;
  TFR(17) TFR(29) TFR(16) TFR(24)
  x0 += ks2; x1 += k0 + 2u;
  TFR(13) TFR(15) TFR(26) TFR(6)
  x0 += k0;  x1 += k1 + 3u;
  TFR(17) TFR(29) TFR(16) TFR(24)
  x0 += k1;  x1 += ks2 + 4u;
  TFR(13) TFR(15) TFR(26) TFR(6)
  x0 += ks2; x1 += k0 + 5u;
#undef TFR
  o0 = x0; o1 = x1;
}

// ============== software grid barrier (device-scope, sense via generation) ====
__device__ __forceinline__ void gsync(unsigned* __restrict__ bar){
  __syncthreads();
  if (threadIdx.x == 0){
    __threadfence();
    unsigned g = __hip_atomic_load(&bar[1], __ATOMIC_RELAXED, __HIP_MEMORY_SCOPE_AGENT);
    unsigned a = __hip_atomic_fetch_add(&bar[0], 1u, __ATOMIC_ACQ_REL, __HIP_MEMORY_SCOPE_AGENT);
    if (a == (unsigned)PB - 1u){
      __hip_atomic_store(&bar[0], 0u, __ATOMIC_RELAXED, __HIP_MEMORY_SCOPE_AGENT);
      __hip_atomic_fetch_add(&bar[1], 1u, __ATOMIC_ACQ_REL, __HIP_MEMORY_SCOPE_AGENT);
    } else {
      while (__hip_atomic_load(&bar[1], __ATOMIC_ACQUIRE, __HIP_MEMORY_SCOPE_AGENT) == g)
        __builtin_amdgcn_s_sleep(2);
    }
    __threadfence();
  }
  __syncthreads();
}

#define SMEM_BYTES 33792   // max phase need: GEMM NT=8 (32768 W + 1024 BN)

// ====== phase bodies (vb = virtual block id; smem = shared scratch) ======

__device__ __forceinline__ void init_body(int vb,
                                          const float* __restrict__ W1,
                                          const float* __restrict__ W2,
                                          const float* __restrict__ W3,
                                          unsigned short* __restrict__ WT1,
                                          unsigned short* __restrict__ WT2,
                                          unsigned short* __restrict__ WT3,
                                          uint4* __restrict__ zbase, int zwords)
{
  if (vb < 3){
    const float* W; unsigned short* WT; int Cout, Cpad;
    if (vb == 0){ W = W1; WT = WT1; Cout = 128; Cpad = 128; }
    else if (vb == 1){ W = W2; WT = WT2; Cout = 128; Cpad = 128; }
    else { W = W3; WT = WT3; Cout = 40; Cpad = 48; }
    int tot = Cpad * 128;
    for (int i = threadIdx.x; i < tot; i += 256){
      int n = i >> 7, k = i & 127;
      float v = (n < Cout) ? W[k * Cout + n] : 0.f;
      WT[i] = f2bfbits(v);
    }
  } else {
    int idx = (vb - 3) * 256 + threadIdx.x;
    if (idx < zwords) zbase[idx] = make_uint4(0u, 0u, 0u, 0u);
  }
}

__device__ __forceinline__ void countpos_body(int vb,
                                              const int* __restrict__ dst,
                                              int* __restrict__ cnt,
                                              int* __restrict__ pos, int E)
{
  int g = vb * 256 + threadIdx.x;
  int base = g * 4;
  if (base + 3 < E){
    int4 d = ((const int4*)dst)[g];
    int4 p;
    p.x = atomicAdd(&cnt[d.x], 1);
    p.y = atomicAdd(&cnt[d.y], 1);
    p.z = atomicAdd(&cnt[d.z], 1);
    p.w = atomicAdd(&cnt[d.w], 1);
    ((int4*)pos)[g] = p;
  } else {
    for (int j = 0; j < 4; j++){
      int e = base + j;
      if (e < E) pos[e] = atomicAdd(&cnt[dst[e]], 1);
    }
  }
}

__device__ __forceinline__ void blocksum_body(int vb, char* smem,
                                              const int* __restrict__ cnt,
                                              int* __restrict__ bsum, int N)
{
  int* sh = (int*)smem;
  __syncthreads();
  int t = threadIdx.x;
  int base = vb * 1024 + t * 4;
  int s = 0;
  #pragma unroll
  for (int j = 0; j < 4; j++){ int i = base + j; if (i < N) s += cnt[i]; }
  sh[t] = s; __syncthreads();
  for (int off = 128; off; off >>= 1){
    if (t < off) sh[t] += sh[t + off];
    __syncthreads();
  }
  if (t == 0) bsum[vb] = sh[0];
}

__device__ __forceinline__ void scanfinal_body(int vb, char* smem,
                                               const int* __restrict__ cnt,
                                               const int* __restrict__ bsum,
                                               int* __restrict__ rowstart,
                                               float* __restrict__ dinv,
                                               int NB, int N)
{
  int* sh = (int*)smem;
  __syncthreads();
  int t = threadIdx.x;
  int vb2 = (t < NB) ? bsum[t] : 0;
  sh[t] = vb2; __syncthreads();
  for (int off = 1; off < 256; off <<= 1){
    int x = sh[t];
    int y = (t >= off) ? sh[t - off] : 0;
    __syncthreads();
    sh[t] = x + y;
    __syncthreads();
  }
  if (vb == 0 && t == 0) rowstart[N] = sh[NB - 1];
  int boffb = sh[vb] - bsum[vb];
  __syncthreads();
  int base = vb * 1024 + t * 4;
  int c0 = 0, c1 = 0, c2 = 0, c3 = 0;
  if (base + 0 < N) c0 = cnt[base + 0];
  if (base + 1 < N) c1 = cnt[base + 1];
  if (base + 2 < N) c2 = cnt[base + 2];
  if (base + 3 < N) c3 = cnt[base + 3];
  int s = c0 + c1 + c2 + c3;
  sh[t] = s; __syncthreads();
  for (int off = 1; off < 256; off <<= 1){
    int x = sh[t];
    int y = (t >= off) ? sh[t - off] : 0;
    __syncthreads();
    sh[t] = x + y;
    __syncthreads();
  }
  int excl = sh[t] - s + boffb;
  if (base + 0 < N){ rowstart[base+0] = excl;          dinv[base+0] = rsqrtf((float)c0 + 1.f); }
  if (base + 1 < N){ rowstart[base+1] = excl+c0;       dinv[base+1] = rsqrtf((float)c1 + 1.f); }
  if (base + 2 < N){ rowstart[base+2] = excl+c0+c1;    dinv[base+2] = rsqrtf((float)c2 + 1.f); }
  if (base + 3 < N){ rowstart[base+3] = excl+c0+c1+c2; dinv[base+3] = rsqrtf((float)c3 + 1.f); }
}

__device__ __forceinline__ void fill_body(int bid,
                                          const int* __restrict__ src,
                                          const int* __restrict__ dst,
                                          const int* __restrict__ pos,
                                          const int* __restrict__ rowstart,
                                          int* __restrict__ csr, int E)
{
  int g = bid * 256 + threadIdx.x;
  int base = g * 4;
  if (base + 3 < E){
    int4 d = ((const int4*)dst)[g];
    int4 p = ((const int4*)pos)[g];
    int4 s = ((const int4*)src)[g];
    int r0 = rowstart[d.x], r1 = rowstart[d.y], r2 = rowstart[d.z], r3 = rowstart[d.w];
    csr[r0 + p.x] = s.x;
    csr[r1 + p.y] = s.y;
    csr[r2 + p.z] = s.z;
    csr[r3 + p.w] = s.w;
  } else {
    for (int j = 0; j < 4; j++){
      int e = base + j;
      if (e < E) csr[rowstart[dst[e]] + pos[e]] = src[e];
    }
  }
}

// GEMM body — swapped operands (C^T fragments), direct-from-global A (R12)
template<int NT, int MODE, int MASKGEN>
__device__ __forceinline__ void gemm_body(int bid, char* smem,
                                          const void* __restrict__ Ap,
                                          const unsigned short* __restrict__ WT,
                                          const float* __restrict__ dinv,
                                          const float* __restrict__ stats,
                                          const float* __restrict__ g,
                                          const float* __restrict__ be,
                                          const unsigned* __restrict__ mask,
                                          unsigned* __restrict__ maskw,
                                          unsigned wk0, unsigned wk1, int Mw,
                                          float invN,
                                          unsigned short* __restrict__ outb,
                                          int N, int Cstride)
{
  uint4* Wl4 = (uint4*)smem;                       // NT*16*16 uint4
  float* bnS = (float*)(smem + NT * 4096);
  float* bnB = bnS + 128;
  __syncthreads();                                 // smem reuse across iterations
  const int t = threadIdx.x;
  const int w = t >> 6, l = t & 63;
  const int lm = l & 15, q = l >> 4;
  const long rb0 = (long)bid * 64;
  const int wrow0 = w * 16;
  const long grow = rb0 + wrow0 + lm;
  const bool inr = (grow < N);

  uint4 rawU[4];
  float4 rawF[4][2];
  uint4 mws;
  if (inr){
    #pragma unroll
    for (int kt = 0; kt < 4; kt++){
      int c = kt * 4 + q;
      if (MODE == 0){
        const float* ap = (const float*)Ap + grow * 128 + c * 8;
        rawF[kt][0] = *(const float4*)ap;
        rawF[kt][1] = *(const float4*)(ap + 4);
      } else {
        rawU[kt] = *(const uint4*)((const unsigned short*)Ap + grow * 128 + c * 8);
      }
    }
    if (MODE == 2) mws = *(const uint4*)(mask + ((unsigned)grow << 2));
  }

  {
    const uint4* s4 = (const uint4*)WT;
    const int tot = NT * 16 * 16;
    for (int i = t; i < tot; i += 256){
      int n = i >> 4, c = i & 15;
      Wl4[n * 16 + (c ^ (n & 15))] = s4[i];
    }
  }
  if (MODE == 2 && t < 128){
    float ss = 0.f, qq = 0.f;
    #pragma unroll
    for (int i = 0; i < 16; i++){
      ss += stats[i * 256 + t];
      qq += stats[i * 256 + 128 + t];
    }
    float mean = ss * invN;
    float var = fmaxf(qq * invN - mean * mean, 0.f);
    float rstd = rsqrtf(var + 1e-5f);
    float sc = g[t] * rstd;
    bnS[t] = sc * 2.f;                       // dropout scale folded in
    bnB[t] = (be[t] - mean * sc) * 2.f;
  }
  __syncthreads();

  bf16x8 afr[4];
  #pragma unroll
  for (int kt = 0; kt < 4; kt++){
    uint4 chunk = make_uint4(0u, 0u, 0u, 0u);
    if (inr){
      if (MODE == 0){
        chunk.x = (unsigned)f2bfbits(rawF[kt][0].x) | ((unsigned)f2bfbits(rawF[kt][0].y) << 16);
        chunk.y = (unsigned)f2bfbits(rawF[kt][0].z) | ((unsigned)f2bfbits(rawF[kt][0].w) << 16);
        chunk.z = (unsigned)f2bfbits(rawF[kt][1].x) | ((unsigned)f2bfbits(rawF[kt][1].y) << 16);
        chunk.w = (unsigned)f2bfbits(rawF[kt][1].z) | ((unsigned)f2bfbits(rawF[kt][1].w) << 16);
      } else {
        int c = kt * 4 + q;
        unsigned mb = (&mws.x)[kt] >> (q * 8);
        const unsigned* rw = &rawU[kt].x;
        unsigned* cw = &chunk.x;
        #pragma unroll
        for (int h = 0; h < 4; h++){
          int ch = c * 8 + 2 * h;
          float f0 = bfbits2f((unsigned short)(rw[h] & 0xffffu));
          float f1 = bfbits2f((unsigned short)(rw[h] >> 16));
          f0 = fmaxf(fmaf(f0, bnS[ch],     bnB[ch]),     0.f);
          f1 = fmaxf(fmaf(f1, bnS[ch + 1], bnB[ch + 1]), 0.f);
          f0 = ((mb >> (2 * h))     & 1u) ? 0.f : f0;
          f1 = ((mb >> (2 * h + 1)) & 1u) ? 0.f : f1;
          cw[h] = (unsigned)f2bfbits(f0) | ((unsigned)f2bfbits(f1) << 16);
        }
      }
    }
    afr[kt] = *(bf16x8*)&chunk;
  }

  f32x4 acc[NT];
  #pragma unroll
  for (int nt = 0; nt < NT; nt++){
    acc[nt][0] = 0.f; acc[nt][1] = 0.f; acc[nt][2] = 0.f; acc[nt][3] = 0.f;
  }

  #pragma unroll
  for (int kt = 0; kt < 4; kt++){
    const int x = kt * 4 + q;
    #pragma unroll
    for (int nt = 0; nt < NT; nt++){
      int brow = nt * 16 + lm;
      bf16x8 wf = *(const bf16x8*)&Wl4[brow * 16 + (x ^ (brow & 15))];
      acc[nt] = __builtin_amdgcn_mfma_f32_16x16x32_bf16(wf, afr[kt], acc[nt], 0, 0, 0);
    }
  }

  if (inr){
    float dv = dinv[grow];
    char* rowp = (char*)outb + (size_t)grow * (unsigned)Cstride * 2u + (unsigned)(q * 4) * 2u;
    #pragma unroll
    for (int nt = 0; nt < NT; nt++){
      uint2 o;
      o.x = (unsigned)f2bfbits(acc[nt][0] * dv) | ((unsigned)f2bfbits(acc[nt][1] * dv) << 16);
      o.y = (unsigned)f2bfbits(acc[nt][2] * dv) | ((unsigned)f2bfbits(acc[nt][3] * dv) << 16);
      *(uint2*)(rowp + nt * 32) = o;
    }
  }

  if (MASKGEN){
    int gg = bid * 256 + t;
    if (gg < Mw){
      unsigned bits = 0u;
      #pragma unroll 4
      for (int j = 0; j < 32; j++){
        unsigned w0, w1;
        tf2x32(wk0, wk1, 0u, (unsigned)gg * 32u + (unsigned)j, w0, w1);
        bits |= (((w0 ^ w1) >> 31) << j);
      }
      maskw[gg] = bits;
    }
  }
}

// agg128 body — R12 single-chain version, flat 256 threads
#define ACC8(U) do{ uint4 _u = (U); \
  a0 += __uint_as_float(_u.x << 16); \
  a1 += __uint_as_float(_u.x & 0xffff0000u); \
  a2 += __uint_as_float(_u.y << 16); \
  a3 += __uint_as_float(_u.y & 0xffff0000u); \
  a4 += __uint_as_float(_u.z << 16); \
  a5 += __uint_as_float(_u.z & 0xffff0000u); \
  a6 += __uint_as_float(_u.w << 16); \
  a7 += __uint_as_float(_u.w & 0xffff0000u); }while(0)

__device__ __forceinline__ void agg128_body(int vb, char* smem,
                                            const unsigned short* __restrict__ hw,
                                            const int* __restrict__ rs,
                                            const int* __restrict__ csr,
                                            const float* __restrict__ dinv,
                                            unsigned short* __restrict__ outb,
                                            float* __restrict__ stats,
                                            int N)
{
  float (*shS)[128] = (float(*)[128])smem;            // 16x128 f32 = 8 KB
  float (*shQ)[128] = (float(*)[128])(smem + 8192);   // 8 KB
  __syncthreads();                                    // smem reuse across iterations
  const int tt = threadIdx.x;
  const int l = tt & 63;
  const int ty = tt >> 6;
  const int ns = l >> 4;
  const int sl = l & 15;
  const int grp = ty * 4 + ns;
  const int base = vb * 32;
  const unsigned slB = (unsigned)sl * 16u;

  float s0=0.f,s1=0.f,s2=0.f,s3=0.f,s4=0.f,s5=0.f,s6=0.f,s7=0.f;
  float q0=0.f,q1=0.f,q2=0.f,q3=0.f,q4=0.f,q5=0.f,q6=0.f,q7=0.f;

  #pragma unroll 1
  for (int it = 0; it < 2; it++){
    int v = base + it * 16 + grp;
    if (v < N){
      float a0=0.f,a1=0.f,a2=0.f,a3=0.f,a4=0.f,a5=0.f,a6=0.f,a7=0.f;
      ACC8(ld16(hw, (unsigned)v * 256u + slB));
      int e0 = rs[v], e1 = rs[v + 1];
      int i = e0;
      for (; i + 4 <= e1; i += 4){
        int sa = csr[i], sb = csr[i+1], sc = csr[i+2], sd = csr[i+3];
        uint4 m0 = ld16(hw, (unsigned)sa * 256u + slB);
        uint4 m1 = ld16(hw, (unsigned)sb * 256u + slB);
        uint4 m2 = ld16(hw, (unsigned)sc * 256u + slB);
        uint4 m3 = ld16(hw, (unsigned)sd * 256u + slB);
        ACC8(m0); ACC8(m1); ACC8(m2); ACC8(m3);
      }
      for (; i < e1; i++){
        ACC8(ld16(hw, (unsigned)csr[i] * 256u + slB));
      }
      float dv = dinv[v];
      a0*=dv; a1*=dv; a2*=dv; a3*=dv; a4*=dv; a5*=dv; a6*=dv; a7*=dv;
      uint4 o;
      o.x = (unsigned)f2bfbits(a0) | ((unsigned)f2bfbits(a1) << 16);
      o.y = (unsigned)f2bfbits(a2) | ((unsigned)f2bfbits(a3) << 16);
      o.z = (unsigned)f2bfbits(a4) | ((unsigned)f2bfbits(a5) << 16);
      o.w = (unsigned)f2bfbits(a6) | ((unsigned)f2bfbits(a7) << 16);
      *(uint4*)((char*)outb + (unsigned)v * 256u + slB) = o;
      s0+=a0; q0=fmaf(a0,a0,q0);  s1+=a1; q1=fmaf(a1,a1,q1);
      s2+=a2; q2=fmaf(a2,a2,q2);  s3+=a3; q3=fmaf(a3,a3,q3);
      s4+=a4; q4=fmaf(a4,a4,q4);  s5+=a5; q5=fmaf(a5,a5,q5);
      s6+=a6; q6=fmaf(a6,a6,q6);  s7+=a7; q7=fmaf(a7,a7,q7);
    }
  }

  *(float4*)&shS[grp][sl * 8]     = make_float4(s0, s1, s2, s3);
  *(float4*)&shS[grp][sl * 8 + 4] = make_float4(s4, s5, s6, s7);
  *(float4*)&shQ[grp][sl * 8]     = make_float4(q0, q1, q2, q3);
  *(float4*)&shQ[grp][sl * 8 + 4] = make_float4(q4, q5, q6, q7);
  __syncthreads();
  if (tt < 128){
    float ss = 0.f, qq = 0.f;
    #pragma unroll
    for (int g2 = 0; g2 < 16; g2++){ ss += shS[g2][tt]; qq += shQ[g2][tt]; }
    float* dstat = stats + (vb & 15) * 256;
    atomicAdd(&dstat[tt], ss);
    atomicAdd(&dstat[128 + tt], qq);
  }
}

// agg40 + log_softmax body — flat 256 threads, no smem
__device__ __forceinline__ void agg40_body(int vb,
                                           const unsigned short* __restrict__ hw,
                                           const int* __restrict__ rs,
                                           const int* __restrict__ csr,
                                           const float* __restrict__ dinv,
                                           const float* __restrict__ b3,
                                           float* __restrict__ out, int N)
{
  const int tt = threadIdx.x;
  const int l = tt & 63;
  const int ty = tt >> 6;
  const int ns = l >> 4, sl = l & 15;
  const int v = vb * 16 + ty * 4 + ns;
  const bool act = (v < N) && (sl < 10);
  const unsigned slB = (unsigned)sl * 8u;
  float a0 = 0.f, a1 = 0.f, a2 = 0.f, a3 = 0.f, dv = 1.f;
  if (act){
    dv = dinv[v];
    uint2 u = ld8(hw, (unsigned)v * 128u + slB);
    a0 = __uint_as_float(u.x << 16);
    a1 = __uint_as_float(u.x & 0xffff0000u);
    a2 = __uint_as_float(u.y << 16);
    a3 = __uint_as_float(u.y & 0xffff0000u);
    int e0 = rs[v], e1 = rs[v + 1];
    int i = e0;
#define ACCU2(U) do{ uint2 _u = (U); \
    a0 += __uint_as_float(_u.x << 16); \
    a1 += __uint_as_float(_u.x & 0xffff0000u); \
    a2 += __uint_as_float(_u.y << 16); \
    a3 += __uint_as_float(_u.y & 0xffff0000u); }while(0)
    for (; i + 4 <= e1; i += 4){
      int sa = csr[i], sb = csr[i+1], sc = csr[i+2], sd = csr[i+3];
      uint2 m0 = ld8(hw, (unsigned)sa * 128u + slB);
      uint2 m1 = ld8(hw, (unsigned)sb * 128u + slB);
      uint2 m2 = ld8(hw, (unsigned)sc * 128u + slB);
      uint2 m3 = ld8(hw, (unsigned)sd * 128u + slB);
      ACCU2(m0); ACCU2(m1); ACCU2(m2); ACCU2(m3);
    }
    for (; i < e1; i++){
      ACCU2(ld8(hw, (unsigned)csr[i] * 128u + slB));
    }
#undef ACCU2
  }
  float x0 = act ? fmaf(a0, dv, b3[sl * 4 + 0]) : -INFINITY;
  float x1 = act ? fmaf(a1, dv, b3[sl * 4 + 1]) : -INFINITY;
  float x2 = act ? fmaf(a2, dv, b3[sl * 4 + 2]) : -INFINITY;
  float x3 = act ? fmaf(a3, dv, b3[sl * 4 + 3]) : -INFINITY;
  float m = fmaxf(fmaxf(x0, x1), fmaxf(x2, x3));
  #pragma unroll
  for (int off = 8; off; off >>= 1) m = fmaxf(m, __shfl_xor(m, off, 16));
  float e = act ? (expf(x0 - m) + expf(x1 - m) + expf(x2 - m) + expf(x3 - m)) : 0.f;
  #pragma unroll
  for (int off = 8; off; off >>= 1) e += __shfl_xor(e, off, 16);
  float lse = m + logf(e);
  if (act){
    float4 o;
    o.x = x0 - lse; o.y = x1 - lse; o.z = x2 - lse; o.w = x3 - lse;
    *reinterpret_cast<float4*>(out + (size_t)v * 40 + sl * 4) = o;
  }
}

// ================= persistent mega-kernel: whole pipeline, 10 phases ==========
__global__ __launch_bounds__(256, 4) void k_mega(
    const float* __restrict__ x, const int* __restrict__ srcv,
    const int* __restrict__ dstv,
    const float* __restrict__ W1, const float* __restrict__ W2,
    const float* __restrict__ W3,
    const float* __restrict__ g1, const float* __restrict__ be1,
    const float* __restrict__ g2, const float* __restrict__ be2,
    const float* __restrict__ b3,
    unsigned* __restrict__ bar,
    int* __restrict__ cnt, float* __restrict__ stats1, float* __restrict__ stats2,
    int* __restrict__ pos, int* __restrict__ rowstart, int* __restrict__ csr,
    float* __restrict__ dinv, int* __restrict__ bsum,
    unsigned* __restrict__ mask1, unsigned* __restrict__ mask2,
    unsigned short* __restrict__ WT1, unsigned short* __restrict__ WT2,
    unsigned short* __restrict__ WT3,
    unsigned short* __restrict__ bufX, unsigned short* __restrict__ bufY,
    float* __restrict__ out,
    unsigned l1k0, unsigned l1k1, unsigned l2k0, unsigned l2k1,
    float invN, int M, int zwords, int N, int E)
{
  __shared__ __align__(16) char smem[SMEM_BYTES];
  const int bx = blockIdx.x;
  const int eg = (E + 1023) / 1024;
  const int NB = (N + 1023) / 1024;
  const int gg = (N + 63) / 64;
  const int wg32 = (N + 31) / 32;
  const int wg16 = (N + 15) / 16;
  const int zg = 3 + (zwords + 255) / 256;

  // phase 0: weight transpose + zero cnt/stats
  for (int vb = bx; vb < zg; vb += PB)
    init_body(vb, W1, W2, W3, WT1, WT2, WT3, (uint4*)cnt, zwords);
  gsync(bar);
  // phase 1: degree count + slot positions
  for (int vb = bx; vb < eg; vb += PB)
    countpos_body(vb, dstv, cnt, pos, E);
  gsync(bar);
  // phase 2: per-1024-chunk sums
  for (int vb = bx; vb < NB; vb += PB)
    blocksum_body(vb, smem, cnt, bsum, N);
  gsync(bar);
  // phase 3: rowstart scan + dinv
  for (int vb = bx; vb < NB; vb += PB)
    scanfinal_body(vb, smem, cnt, bsum, rowstart, dinv, NB, N);
  gsync(bar);
  // phase 4: GEMM1 (+ mask1 gen) merged with CSR fill
  for (int vb = bx; vb < gg + eg; vb += PB){
    if (vb < gg)
      gemm_body<8, 0, 1>(vb, smem, x, WT1, dinv, nullptr, nullptr, nullptr,
                         nullptr, mask1, l1k0, l1k1, M, 0.f, bufX, N, 128);
    else
      fill_body(vb - gg, srcv, dstv, pos, rowstart, csr, E);
  }
  gsync(bar);
  // phase 5: aggregation layer 1 (+ BN1 stats)
  for (int vb = bx; vb < wg32; vb += PB)
    agg128_body(vb, smem, bufX, rowstart, csr, dinv, bufY, stats1, N);
  gsync(bar);
  // phase 6: GEMM2 (BN1+ReLU+dropout fused; + mask2 gen)
  for (int vb = bx; vb < gg; vb += PB)
    gemm_body<8, 2, 1>(vb, smem, bufY, WT2, dinv, stats1, g1, be1,
                       mask1, mask2, l2k0, l2k1, M, invN, bufX, N, 128);
  gsync(bar);
  // phase 7: aggregation layer 2 (+ BN2 stats)
  for (int vb = bx; vb < wg32; vb += PB)
    agg128_body(vb, smem, bufX, rowstart, csr, dinv, bufY, stats2, N);
  gsync(bar);
  // phase 8: GEMM3 (BN2+ReLU+dropout fused), 64-ch padded rows
  for (int vb = bx; vb < gg; vb += PB)
    gemm_body<3, 2, 0>(vb, smem, bufY, WT3, dinv, stats2, g2, be2,
                       mask2, nullptr, 0u, 0u, 0, invN, bufX, N, 64);
  gsync(bar);
  // phase 9: aggregation layer 3 + bias + log_softmax
  for (int vb = bx; vb < wg16; vb += PB)
    agg40_body(vb, bufX, rowstart, csr, dinv, b3, out, N);
}

// ================= launch =================
extern "C" void kernel_launch(void* const* d_in, const int* in_sizes, int n_in,
                              void* d_out, int out_size, void* d_ws, size_t ws_size,
                              hipStream_t stream)
{
  const float* x  = (const float*)d_in[0];
  const int* ei   = (const int*)d_in[1];
  const float* W1 = (const float*)d_in[2];
  const float* g1 = (const float*)d_in[4];
  const float* be1= (const float*)d_in[5];
  const float* W2 = (const float*)d_in[6];
  const float* g2 = (const float*)d_in[8];
  const float* be2= (const float*)d_in[9];
  const float* W3 = (const float*)d_in[10];
  const float* b3 = (const float*)d_in[11];
  float* out = (float*)d_out;
  // b1, b2 unused: per-channel constants cancel exactly in training-mode BN.

  const int N = in_sizes[0] / 128;
  const int E = in_sizes[1] / 2;
  const int* srcv = ei;
  const int* dstv = ei + E;

  char* ws = (char*)d_ws;
  size_t off = 0;
  auto take = [&](size_t bytes) -> void* {
    void* p = ws + off;
    off = (off + bytes + 255) & ~(size_t)255;
    return p;
  };
  unsigned* bar   = (unsigned*)take(2 * 4);            // grid barrier state
  // cnt and stats adjacent: zeroed by phase 0 in one pass
  size_t zstart = off;
  int*   cnt      = (int*)  take((size_t)N * 4);
  float* stats1   = (float*)take(2 * 16 * 256 * 4);
  float* stats2   = stats1 + 16 * 256;
  size_t zlen = off - zstart;
  int*   pos      = (int*)  take((size_t)E * 4);
  int*   rowstart = (int*)  take((size_t)(N + 1) * 4);
  int*   csr      = (int*)  take((size_t)E * 4);
  float* dinv     = (float*)take((size_t)N * 4);
  int*   bsum     = (int*)  take(256 * 4);
  unsigned* mask1 = (unsigned*)take((size_t)N * 4 * 4);
  unsigned* mask2 = (unsigned*)take((size_t)N * 4 * 4);
  unsigned short* WT1 = (unsigned short*)take(128 * 128 * 2);
  unsigned short* WT2 = (unsigned short*)take(128 * 128 * 2);
  unsigned short* WT3 = (unsigned short*)take(48 * 128 * 2);
  unsigned short* bufX = (unsigned short*)take((size_t)N * 128 * 2);
  unsigned short* bufY = (unsigned short*)take((size_t)N * 128 * 2);
  (void)ws_size; (void)n_in; (void)out_size;

  // dropout subkeys: jax.random.split(key(42), 2), partitionable fold
  unsigned l1k0, l1k1, l2k0, l2k1;
  tf2x32(0u, 42u, 0u, 0u, l1k0, l1k1);
  tf2x32(0u, 42u, 0u, 1u, l2k0, l2k1);

  const float invN = 1.0f / (float)N;
  const int M = N * 4;
  const int zwords = (int)(zlen / 16);

  hipMemsetAsync(bar, 0, 2 * 4, stream);
  k_mega<<<PB, 256, 0, stream>>>(x, srcv, dstv, W1, W2, W3,
      g1, be1, g2, be2, b3, bar,
      cnt, stats1, stats2, pos, rowstart, csr, dinv, bsum,
      mask1, mask2, WT1, WT2, WT3, bufX, bufY, out,
      l1k0, l1k1, l2k0, l2k1, invN, M, zwords, N, E);
}

// Round 16
// 392.600 us; speedup vs baseline: 3.8817x; 3.8817x over previous
//
#include <hip/hip_runtime.h>
#include <math.h>

typedef __attribute__((ext_vector_type(8))) short bf16x8;
typedef __attribute__((ext_vector_type(4))) float f32x4;

__device__ __forceinline__ float bfbits2f(unsigned short b){
  return __uint_as_float(((unsigned)b) << 16);
}
__device__ __forceinline__ unsigned short f2bfbits(float f){
  unsigned u = __float_as_uint(f);
  unsigned r = u + 0x7fffu + ((u >> 16) & 1u);
  return (unsigned short)(r >> 16);
}

// 32-bit-offset gather helpers: uniform SGPR base + unsigned byte offset
__device__ __forceinline__ uint4 ld16(const void* __restrict__ base, unsigned byteoff){
  return *(const uint4*)((const char*)base + byteoff);
}
__device__ __forceinline__ uint2 ld8(const void* __restrict__ base, unsigned byteoff){
  return *(const uint2*)((const char*)base + byteoff);
}

// ================= Threefry-2x32 (JAX partitionable) =================
__host__ __device__ __forceinline__ unsigned rotl32(unsigned v, int d){
  return (v << d) | (v >> (32 - d));
}
__host__ __device__ __forceinline__ void tf2x32(unsigned k0, unsigned k1,
                                                unsigned c0, unsigned c1,
                                                unsigned &o0, unsigned &o1)
{
  unsigned ks2 = k0 ^ k1 ^ 0x1BD11BDAu;
  unsigned x0 = c0 + k0, x1 = c1 + k1;
#define TFR(r) x0 += x1; x1 = rotl32(x1, r); x1 ^= x0;
  TFR(13) TFR(15) TFR(26) TFR(6)
  x0 += k1;  x1 += ks2 + 1u;
  TFR(17) TFR(29) TFR(16) TFR(24)
  x0 += ks2; x1 += k0 + 2u;
  TFR(13) TFR(15) TFR(26) TFR(6)
  x0 += k0;  x1 += k1 + 3u;
  TFR(17) TFR(29) TFR(16) TFR(24)
  x0 += k1;  x1 += ks2 + 4u;
  TFR(13) TFR(15) TFR(26) TFR(6)
  x0 += ks2; x1 += k0 + 5u;
#undef TFR
  o0 = x0; o1 = x1;
}

// ====== init: weight transpose (3 blocks) + zero cnt/stats (rest) ======
__global__ __launch_bounds__(256) void k_init(const float* __restrict__ W1,
                                              const float* __restrict__ W2,
                                              const float* __restrict__ W3,
                                              unsigned short* __restrict__ WT1,
                                              unsigned short* __restrict__ WT2,
                                              unsigned short* __restrict__ WT3,
                                              uint4* __restrict__ zbase, int zwords)
{
  if (blockIdx.x < 3){
    const float* W; unsigned short* WT; int Cout, Cpad;
    if (blockIdx.x == 0){ W = W1; WT = WT1; Cout = 128; Cpad = 128; }
    else if (blockIdx.x == 1){ W = W2; WT = WT2; Cout = 128; Cpad = 128; }
    else { W = W3; WT = WT3; Cout = 40; Cpad = 48; }
    int tot = Cpad * 128;
    for (int i = threadIdx.x; i < tot; i += 256){
      int n = i >> 7, k = i & 127;
      float v = (n < Cout) ? W[k * Cout + n] : 0.f;
      WT[i] = f2bfbits(v);
    }
  } else {
    int idx = (blockIdx.x - 3) * 256 + threadIdx.x;
    if (idx < zwords) zbase[idx] = make_uint4(0u, 0u, 0u, 0u);
  }
}

// ================= CSR build (two-pass: pos precomputed) ========
__global__ __launch_bounds__(256) void k_countpos(const int* __restrict__ dst,
                                                  int* __restrict__ cnt,
                                                  int* __restrict__ pos, int E)
{
  int g = blockIdx.x * 256 + threadIdx.x;
  int base = g * 4;
  if (base + 3 < E){
    int4 d = ((const int4*)dst)[g];
    int4 p;
    p.x = atomicAdd(&cnt[d.x], 1);
    p.y = atomicAdd(&cnt[d.y], 1);
    p.z = atomicAdd(&cnt[d.z], 1);
    p.w = atomicAdd(&cnt[d.w], 1);
    ((int4*)pos)[g] = p;
  } else {
    for (int j = 0; j < 4; j++){
      int e = base + j;
      if (e < E) pos[e] = atomicAdd(&cnt[dst[e]], 1);
    }
  }
}

__global__ __launch_bounds__(256) void k_blocksum(const int* __restrict__ cnt,
                                                  int* __restrict__ bsum, int N)
{
  __shared__ int sh[256];
  int t = threadIdx.x;
  int base = blockIdx.x * 1024 + t * 4;
  int s = 0;
  #pragma unroll
  for (int j = 0; j < 4; j++){ int i = base + j; if (i < N) s += cnt[i]; }
  sh[t] = s; __syncthreads();
  for (int off = 128; off; off >>= 1){
    if (t < off) sh[t] += sh[t + off];
    __syncthreads();
  }
  if (t == 0) bsum[blockIdx.x] = sh[0];
}

// scanfinal with the bsum scan inlined per block
__global__ __launch_bounds__(256) void k_scanfinal(const int* __restrict__ cnt,
                                                   const int* __restrict__ bsum,
                                                   int* __restrict__ rowstart,
                                                   float* __restrict__ dinv,
                                                   int NB, int N)
{
  __shared__ int sh[256];
  int t = threadIdx.x;
  int vb = (t < NB) ? bsum[t] : 0;
  sh[t] = vb; __syncthreads();
  for (int off = 1; off < 256; off <<= 1){
    int x = sh[t];
    int y = (t >= off) ? sh[t - off] : 0;
    __syncthreads();
    sh[t] = x + y;
    __syncthreads();
  }
  if (blockIdx.x == 0 && t == 0) rowstart[N] = sh[NB - 1];
  int boffb = sh[blockIdx.x] - bsum[blockIdx.x];
  __syncthreads();
  int base = blockIdx.x * 1024 + t * 4;
  int c0 = 0, c1 = 0, c2 = 0, c3 = 0;
  if (base + 0 < N) c0 = cnt[base + 0];
  if (base + 1 < N) c1 = cnt[base + 1];
  if (base + 2 < N) c2 = cnt[base + 2];
  if (base + 3 < N) c3 = cnt[base + 3];
  int s = c0 + c1 + c2 + c3;
  sh[t] = s; __syncthreads();
  for (int off = 1; off < 256; off <<= 1){
    int x = sh[t];
    int y = (t >= off) ? sh[t - off] : 0;
    __syncthreads();
    sh[t] = x + y;
    __syncthreads();
  }
  int excl = sh[t] - s + boffb;
  if (base + 0 < N){ rowstart[base+0] = excl;          dinv[base+0] = rsqrtf((float)c0 + 1.f); }
  if (base + 1 < N){ rowstart[base+1] = excl+c0;       dinv[base+1] = rsqrtf((float)c1 + 1.f); }
  if (base + 2 < N){ rowstart[base+2] = excl+c0+c1;    dinv[base+2] = rsqrtf((float)c2 + 1.f); }
  if (base + 3 < N){ rowstart[base+3] = excl+c0+c1+c2; dinv[base+3] = rsqrtf((float)c3 + 1.f); }
}

// fill body (device fn so it can merge with GEMM1)
__device__ __forceinline__ void fill_body(int bid,
                                          const int* __restrict__ src,
                                          const int* __restrict__ dst,
                                          const int* __restrict__ pos,
                                          const int* __restrict__ rowstart,
                                          int* __restrict__ csr, int E)
{
  int g = bid * 256 + threadIdx.x;
  int base = g * 4;
  if (base + 3 < E){
    int4 d = ((const int4*)dst)[g];
    int4 p = ((const int4*)pos)[g];
    int4 s = ((const int4*)src)[g];
    int r0 = rowstart[d.x], r1 = rowstart[d.y], r2 = rowstart[d.z], r3 = rowstart[d.w];
    csr[r0 + p.x] = s.x;
    csr[r1 + p.y] = s.y;
    csr[r2 + p.z] = s.z;
    csr[r3 + p.w] = s.w;
  } else {
    for (int j = 0; j < 4; j++){
      int e = base + j;
      if (e < E) csr[rowstart[dst[e]] + pos[e]] = src[e];
    }
  }
}

// ================= MFMA GEMM body — swapped operands (C^T fragments) ======
// mfma(W_frag, A_frag): thread (q,lm) owns ONE output row (x-row lm) with cols
// {16nt+4q..4q+3}; epilogue is 8 x 8B stores to one row. Dropout *2 folded
// into BN scale/bias (exact: 2*relu(y) = relu(2y)).
template<int NT, int MODE, int MASKGEN>
__device__ __forceinline__ void gemm_body(int bid,
                                          const void* __restrict__ Ap,
                                          const unsigned short* __restrict__ WT,
                                          const float* __restrict__ dinv,
                                          const float* __restrict__ stats,
                                          const float* __restrict__ g,
                                          const float* __restrict__ be,
                                          const unsigned* __restrict__ mask,
                                          unsigned* __restrict__ maskw,
                                          unsigned wk0, unsigned wk1, int Mw,
                                          float invN,
                                          unsigned short* __restrict__ outb,
                                          int N, int Cstride)
{
  __shared__ uint4 Wl4[NT * 16 * 16];          // NT*16 rows x 16 chunks, swizzled
  __shared__ float bnS[128], bnB[128];
  const int t = threadIdx.x;
  const int w = t >> 6, l = t & 63;
  const int lm = l & 15, q = l >> 4;
  const long rb0 = (long)bid * 64;
  const int wrow0 = w * 16;
  const long grow = rb0 + wrow0 + lm;          // the one A-row this lane feeds
  const bool inr = (grow < N);

  // ---- issue own-row A (+mask) loads first (hidden behind W/bn stage) ----
  uint4 rawU[4];
  float4 rawF[4][2];
  uint4 mws;
  if (inr){
    #pragma unroll
    for (int kt = 0; kt < 4; kt++){
      int c = kt * 4 + q;
      if (MODE == 0){
        const float* ap = (const float*)Ap + grow * 128 + c * 8;
        rawF[kt][0] = *(const float4*)ap;
        rawF[kt][1] = *(const float4*)(ap + 4);
      } else {
        rawU[kt] = *(const uint4*)((const unsigned short*)Ap + grow * 128 + c * 8);
      }
    }
    if (MODE == 2) mws = *(const uint4*)(mask + ((unsigned)grow << 2));
  }

  // ---- shared W stage (+ BN prep), single block barrier ----
  {
    const uint4* s4 = (const uint4*)WT;
    const int tot = NT * 16 * 16;
    for (int i = t; i < tot; i += 256){
      int n = i >> 4, c = i & 15;
      Wl4[n * 16 + (c ^ (n & 15))] = s4[i];
    }
  }
  if (MODE == 2 && t < 128){
    float ss = 0.f, qq = 0.f;
    #pragma unroll
    for (int i = 0; i < 16; i++){
      ss += stats[i * 256 + t];
      qq += stats[i * 256 + 128 + t];
    }
    float mean = ss * invN;
    float var = fmaxf(qq * invN - mean * mean, 0.f);
    float rstd = rsqrtf(var + 1e-5f);
    float sc = g[t] * rstd;
    bnS[t] = sc * 2.f;                       // dropout scale folded in
    bnB[t] = (be[t] - mean * sc) * 2.f;
  }
  __syncthreads();

  // ---- transform own-row chunks in registers ----
  bf16x8 afr[4];
  #pragma unroll
  for (int kt = 0; kt < 4; kt++){
    uint4 chunk = make_uint4(0u, 0u, 0u, 0u);
    if (inr){
      if (MODE == 0){
        chunk.x = (unsigned)f2bfbits(rawF[kt][0].x) | ((unsigned)f2bfbits(rawF[kt][0].y) << 16);
        chunk.y = (unsigned)f2bfbits(rawF[kt][0].z) | ((unsigned)f2bfbits(rawF[kt][0].w) << 16);
        chunk.z = (unsigned)f2bfbits(rawF[kt][1].x) | ((unsigned)f2bfbits(rawF[kt][1].y) << 16);
        chunk.w = (unsigned)f2bfbits(rawF[kt][1].z) | ((unsigned)f2bfbits(rawF[kt][1].w) << 16);
      } else {
        int c = kt * 4 + q;
        unsigned mb = (&mws.x)[kt] >> (q * 8);     // 8 drop bits for this chunk
        const unsigned* rw = &rawU[kt].x;
        unsigned* cw = &chunk.x;
        #pragma unroll
        for (int h = 0; h < 4; h++){
          int ch = c * 8 + 2 * h;
          float f0 = bfbits2f((unsigned short)(rw[h] & 0xffffu));
          float f1 = bfbits2f((unsigned short)(rw[h] >> 16));
          f0 = fmaxf(fmaf(f0, bnS[ch],     bnB[ch]),     0.f);
          f1 = fmaxf(fmaf(f1, bnS[ch + 1], bnB[ch + 1]), 0.f);
          f0 = ((mb >> (2 * h))     & 1u) ? 0.f : f0;
          f1 = ((mb >> (2 * h + 1)) & 1u) ? 0.f : f1;
          cw[h] = (unsigned)f2bfbits(f0) | ((unsigned)f2bfbits(f1) << 16);
        }
      }
    }
    afr[kt] = *(bf16x8*)&chunk;
  }

  f32x4 acc[NT];
  #pragma unroll
  for (int nt = 0; nt < NT; nt++){
    acc[nt][0] = 0.f; acc[nt][1] = 0.f; acc[nt][2] = 0.f; acc[nt][3] = 0.f;
  }

  // swapped operands: a = W fragment, b = A fragment  ->  acc holds C^T
  #pragma unroll
  for (int kt = 0; kt < 4; kt++){
    const int x = kt * 4 + q;
    #pragma unroll
    for (int nt = 0; nt < NT; nt++){
      int brow = nt * 16 + lm;
      bf16x8 wf = *(const bf16x8*)&Wl4[brow * 16 + (x ^ (brow & 15))];
      acc[nt] = __builtin_amdgcn_mfma_f32_16x16x32_bf16(wf, afr[kt], acc[nt], 0, 0, 0);
    }
  }

  // ---- epilogue: one row per thread, 8B per nt (4 contiguous channels) ----
  if (inr){
    float dv = dinv[grow];
    char* rowp = (char*)outb + (size_t)grow * (unsigned)Cstride * 2u + (unsigned)(q * 4) * 2u;
    #pragma unroll
    for (int nt = 0; nt < NT; nt++){
      uint2 o;
      o.x = (unsigned)f2bfbits(acc[nt][0] * dv) | ((unsigned)f2bfbits(acc[nt][1] * dv) << 16);
      o.y = (unsigned)f2bfbits(acc[nt][2] * dv) | ((unsigned)f2bfbits(acc[nt][3] * dv) << 16);
      *(uint2*)(rowp + nt * 32) = o;
    }
  }

  // ---- hidden VALU work: next layer's dropout mask (1 word/thread) ----
  if (MASKGEN){
    int gg = bid * 256 + t;
    if (gg < Mw){
      unsigned bits = 0u;
      #pragma unroll 4
      for (int j = 0; j < 32; j++){
        unsigned w0, w1;
        tf2x32(wk0, wk1, 0u, (unsigned)gg * 32u + (unsigned)j, w0, w1);
        bits |= (((w0 ^ w1) >> 31) << j);
      }
      maskw[gg] = bits;
    }
  }
}

// GEMM1 + fill merged (both depend only on scanfinal)
__global__ __launch_bounds__(256) void k_g1f(const void* __restrict__ Ap,
                                             const unsigned short* __restrict__ WT,
                                             const float* __restrict__ dinv,
                                             unsigned* __restrict__ maskw,
                                             unsigned wk0, unsigned wk1, int Mw,
                                             unsigned short* __restrict__ outb, int N,
                                             const int* __restrict__ src,
                                             const int* __restrict__ dst,
                                             const int* __restrict__ pos,
                                             const int* __restrict__ rowstart,
                                             int* __restrict__ csr, int E, int gg)
{
  if ((int)blockIdx.x < gg){
    gemm_body<8, 0, 1>(blockIdx.x, Ap, WT, dinv, nullptr, nullptr, nullptr,
                       nullptr, maskw, wk0, wk1, Mw, 0.f, outb, N, 128);
  } else {
    fill_body(blockIdx.x - gg, src, dst, pos, rowstart, csr, E);
  }
}

template<int NT, int MODE, int MASKGEN>
__global__ __launch_bounds__(256) void k_gemm_mfma(const void* __restrict__ Ap,
                                                   const unsigned short* __restrict__ WT,
                                                   const float* __restrict__ dinv,
                                                   const float* __restrict__ stats,
                                                   const float* __restrict__ g,
                                                   const float* __restrict__ be,
                                                   const unsigned* __restrict__ mask,
                                                   unsigned* __restrict__ maskw,
                                                   unsigned wk0, unsigned wk1, int Mw,
                                                   float invN,
                                                   unsigned short* __restrict__ outb,
                                                   int N, int Cstride)
{
  gemm_body<NT, MODE, MASKGEN>(blockIdx.x, Ap, WT, dinv, stats, g, be, mask,
                               maskw, wk0, wk1, Mw, invN, outb, N, Cstride);
}

// ====== aggregation (128 ch) + fused BN stats ======
#define ACC8(U) do{ uint4 _u = (U); \
  a0 += __uint_as_float(_u.x << 16); \
  a1 += __uint_as_float(_u.x & 0xffff0000u); \
  a2 += __uint_as_float(_u.y << 16); \
  a3 += __uint_as_float(_u.y & 0xffff0000u); \
  a4 += __uint_as_float(_u.z << 16); \
  a5 += __uint_as_float(_u.z & 0xffff0000u); \
  a6 += __uint_as_float(_u.w << 16); \
  a7 += __uint_as_float(_u.w & 0xffff0000u); }while(0)

__global__ __launch_bounds__(256) void k_agg128s(const unsigned short* __restrict__ hw,
                                                 const int* __restrict__ rs,
                                                 const int* __restrict__ csr,
                                                 const float* __restrict__ dinv,
                                                 unsigned short* __restrict__ outb,
                                                 float* __restrict__ stats,
                                                 int N)
{
  const int l = threadIdx.x;
  const int ns = l >> 4;                 // node-sub 0..3
  const int sl = l & 15;                 // sublane 0..15
  const int ty = threadIdx.y;
  const int grp = ty * 4 + ns;           // 0..15 chain id
  const int base = blockIdx.x * 32;
  const unsigned slB = (unsigned)sl * 16u;   // lane byte offset within a 256 B row

  float s0=0.f,s1=0.f,s2=0.f,s3=0.f,s4=0.f,s5=0.f,s6=0.f,s7=0.f;
  float q0=0.f,q1=0.f,q2=0.f,q3=0.f,q4=0.f,q5=0.f,q6=0.f,q7=0.f;

  #pragma unroll 1
  for (int it = 0; it < 2; it++){
    int v = base + it * 16 + grp;
    if (v < N){
      float a0=0.f,a1=0.f,a2=0.f,a3=0.f,a4=0.f,a5=0.f,a6=0.f,a7=0.f;
      ACC8(ld16(hw, (unsigned)v * 256u + slB));
      int e0 = rs[v], e1 = rs[v + 1];
      int i = e0;
      for (; i + 4 <= e1; i += 4){
        int sa = csr[i], sb = csr[i+1], sc = csr[i+2], sd = csr[i+3];
        uint4 m0 = ld16(hw, (unsigned)sa * 256u + slB);
        uint4 m1 = ld16(hw, (unsigned)sb * 256u + slB);
        uint4 m2 = ld16(hw, (unsigned)sc * 256u + slB);
        uint4 m3 = ld16(hw, (unsigned)sd * 256u + slB);
        ACC8(m0); ACC8(m1); ACC8(m2); ACC8(m3);
      }
      for (; i < e1; i++){
        ACC8(ld16(hw, (unsigned)csr[i] * 256u + slB));
      }
      float dv = dinv[v];
      a0*=dv; a1*=dv; a2*=dv; a3*=dv; a4*=dv; a5*=dv; a6*=dv; a7*=dv;
      uint4 o;
      o.x = (unsigned)f2bfbits(a0) | ((unsigned)f2bfbits(a1) << 16);
      o.y = (unsigned)f2bfbits(a2) | ((unsigned)f2bfbits(a3) << 16);
      o.z = (unsigned)f2bfbits(a4) | ((unsigned)f2bfbits(a5) << 16);
      o.w = (unsigned)f2bfbits(a6) | ((unsigned)f2bfbits(a7) << 16);
      *(uint4*)((char*)outb + (unsigned)v * 256u + slB) = o;
      s0+=a0; q0=fmaf(a0,a0,q0);  s1+=a1; q1=fmaf(a1,a1,q1);
      s2+=a2; q2=fmaf(a2,a2,q2);  s3+=a3; q3=fmaf(a3,a3,q3);
      s4+=a4; q4=fmaf(a4,a4,q4);  s5+=a5; q5=fmaf(a5,a5,q5);
      s6+=a6; q6=fmaf(a6,a6,q6);  s7+=a7; q7=fmaf(a7,a7,q7);
    }
  }

  __shared__ float shS[16][128], shQ[16][128];
  *(float4*)&shS[grp][sl * 8]     = make_float4(s0, s1, s2, s3);
  *(float4*)&shS[grp][sl * 8 + 4] = make_float4(s4, s5, s6, s7);
  *(float4*)&shQ[grp][sl * 8]     = make_float4(q0, q1, q2, q3);
  *(float4*)&shQ[grp][sl * 8 + 4] = make_float4(q4, q5, q6, q7);
  __syncthreads();
  int t = ty * 64 + threadIdx.x;
  if (t < 128){
    float ss = 0.f, qq = 0.f;
    #pragma unroll
    for (int g2 = 0; g2 < 16; g2++){ ss += shS[g2][t]; qq += shQ[g2][t]; }
    float* dstat = stats + (blockIdx.x & 15) * 256;
    atomicAdd(&dstat[t], ss);
    atomicAdd(&dstat[128 + t], qq);
  }
}

// ============ layer-3 agg (40 ch) + bias + log_softmax ============
__global__ __launch_bounds__(256) void k_agg40lsm(const unsigned short* __restrict__ hw,
                                                  const int* __restrict__ rs,
                                                  const int* __restrict__ csr,
                                                  const float* __restrict__ dinv,
                                                  const float* __restrict__ b3,
                                                  float* __restrict__ out, int N)
{
  const int l = threadIdx.x;
  const int ns = l >> 4, sl = l & 15;
  const int v = blockIdx.x * 16 + threadIdx.y * 4 + ns;
  const bool act = (v < N) && (sl < 10);
  const unsigned slB = (unsigned)sl * 8u;    // lane byte offset within a 128 B row
  float a0 = 0.f, a1 = 0.f, a2 = 0.f, a3 = 0.f, dv = 1.f;
  if (act){
    dv = dinv[v];
    uint2 u = ld8(hw, (unsigned)v * 128u + slB);
    a0 = __uint_as_float(u.x << 16);
    a1 = __uint_as_float(u.x & 0xffff0000u);
    a2 = __uint_as_float(u.y << 16);
    a3 = __uint_as_float(u.y & 0xffff0000u);
    int e0 = rs[v], e1 = rs[v + 1];
    int i = e0;
#define ACCU2(U) do{ uint2 _u = (U); \
    a0 += __uint_as_float(_u.x << 16); \
    a1 += __uint_as_float(_u.x & 0xffff0000u); \
    a2 += __uint_as_float(_u.y << 16); \
    a3 += __uint_as_float(_u.y & 0xffff0000u); }while(0)
    for (; i + 4 <= e1; i += 4){
      int sa = csr[i], sb = csr[i+1], sc = csr[i+2], sd = csr[i+3];
      uint2 m0 = ld8(hw, (unsigned)sa * 128u + slB);
      uint2 m1 = ld8(hw, (unsigned)sb * 128u + slB);
      uint2 m2 = ld8(hw, (unsigned)sc * 128u + slB);
      uint2 m3 = ld8(hw, (unsigned)sd * 128u + slB);
      ACCU2(m0); ACCU2(m1); ACCU2(m2); ACCU2(m3);
    }
    for (; i < e1; i++){
      ACCU2(ld8(hw, (unsigned)csr[i] * 128u + slB));
    }
#undef ACCU2
  }
  float x0 = act ? fmaf(a0, dv, b3[sl * 4 + 0]) : -INFINITY;
  float x1 = act ? fmaf(a1, dv, b3[sl * 4 + 1]) : -INFINITY;
  float x2 = act ? fmaf(a2, dv, b3[sl * 4 + 2]) : -INFINITY;
  float x3 = act ? fmaf(a3, dv, b3[sl * 4 + 3]) : -INFINITY;
  float m = fmaxf(fmaxf(x0, x1), fmaxf(x2, x3));
  #pragma unroll
  for (int off = 8; off; off >>= 1) m = fmaxf(m, __shfl_xor(m, off, 16));
  float e = act ? (expf(x0 - m) + expf(x1 - m) + expf(x2 - m) + expf(x3 - m)) : 0.f;
  #pragma unroll
  for (int off = 8; off; off >>= 1) e += __shfl_xor(e, off, 16);
  float lse = m + logf(e);
  if (act){
    float4 o;
    o.x = x0 - lse; o.y = x1 - lse; o.z = x2 - lse; o.w = x3 - lse;
    *reinterpret_cast<float4*>(out + (size_t)v * 40 + sl * 4) = o;
  }
}

// ================= launch =================
extern "C" void kernel_launch(void* const* d_in, const int* in_sizes, int n_in,
                              void* d_out, int out_size, void* d_ws, size_t ws_size,
                              hipStream_t stream)
{
  const float* x  = (const float*)d_in[0];
  const int* ei   = (const int*)d_in[1];
  const float* W1 = (const float*)d_in[2];
  const float* g1 = (const float*)d_in[4];
  const float* be1= (const float*)d_in[5];
  const float* W2 = (const float*)d_in[6];
  const float* g2 = (const float*)d_in[8];
  const float* be2= (const float*)d_in[9];
  const float* W3 = (const float*)d_in[10];
  const float* b3 = (const float*)d_in[11];
  float* out = (float*)d_out;
  // b1, b2 unused: per-channel constants cancel exactly in training-mode BN.

  const int N = in_sizes[0] / 128;
  const int E = in_sizes[1] / 2;
  const int* srcv = ei;
  const int* dstv = ei + E;

  char* ws = (char*)d_ws;
  size_t off = 0;
  auto take = [&](size_t bytes) -> void* {
    void* p = ws + off;
    off = (off + bytes + 255) & ~(size_t)255;
    return p;
  };
  // cnt and stats adjacent: zeroed by k_init in one pass
  int*   cnt      = (int*)  take((size_t)N * 4);
  float* stats1   = (float*)take(2 * 16 * 256 * 4);    // two banked stat sets
  float* stats2   = stats1 + 16 * 256;
  size_t zlen = off;                                   // bytes to zero (aligned)
  int*   pos      = (int*)  take((size_t)E * 4);
  int*   rowstart = (int*)  take((size_t)(N + 1) * 4);
  int*   csr      = (int*)  take((size_t)E * 4);
  float* dinv     = (float*)take((size_t)N * 4);
  int*   bsum     = (int*)  take(256 * 4);
  unsigned* mask1 = (unsigned*)take((size_t)N * 4 * 4);  // N*128 bits
  unsigned* mask2 = (unsigned*)take((size_t)N * 4 * 4);
  unsigned short* WT1 = (unsigned short*)take(128 * 128 * 2);
  unsigned short* WT2 = (unsigned short*)take(128 * 128 * 2);
  unsigned short* WT3 = (unsigned short*)take(48 * 128 * 2);
  unsigned short* bufX = (unsigned short*)take((size_t)N * 128 * 2);
  unsigned short* bufY = (unsigned short*)take((size_t)N * 128 * 2);
  (void)ws_size; (void)n_in; (void)out_size;

  // dropout subkeys: jax.random.split(key(42), 2), partitionable fold
  unsigned l1k0, l1k1, l2k0, l2k1;
  tf2x32(0u, 42u, 0u, 0u, l1k0, l1k1);
  tf2x32(0u, 42u, 0u, 1u, l2k0, l2k1);

  const float invN = 1.0f / (float)N;
  const int M = N * 4;                  // mask words (N*128/32)
  const int NB = (N + 1023) / 1024;
  dim3 wblk(64, 4);
  dim3 wgrid16((N + 15) / 16);
  dim3 wgrid32((N + 31) / 32);
  const int ggrid = (N + 63) / 64;
  const int egrid = (E + 1023) / 1024;
  const int zwords = (int)(zlen / 16);
  const int zgrid = 3 + (zwords + 255) / 256;

  // ---- init: weight transpose + zero cnt/stats (1 dispatch) ----
  k_init<<<zgrid, 256, 0, stream>>>(W1, W2, W3, WT1, WT2, WT3, (uint4*)cnt, zwords);
  // ---- CSR build ----
  k_countpos<<<egrid, 256, 0, stream>>>(dstv, cnt, pos, E);
  k_blocksum<<<NB, 256, 0, stream>>>(cnt, bsum, N);
  k_scanfinal<<<NB, 256, 0, stream>>>(cnt, bsum, rowstart, dinv, NB, N);

  // ---- layer 1 GEMM (+ mask1 gen) merged with CSR fill ----
  k_g1f<<<ggrid + egrid, 256, 0, stream>>>(x, WT1, dinv, mask1, l1k0, l1k1, M,
      bufX, N, srcv, dstv, pos, rowstart, csr, E, ggrid);
  k_agg128s<<<wgrid32, wblk, 0, stream>>>(bufX, rowstart, csr, dinv, bufY, stats1, N);

  // ---- layer 2 (BN1+ReLU+dropout fused; + mask2 gen) ----
  k_gemm_mfma<8, 2, 1><<<ggrid, 256, 0, stream>>>(bufY, WT2, dinv,
      stats1, g1, be1, mask1, mask2, l2k0, l2k1, M,
      invN, bufX, N, 128);
  k_agg128s<<<wgrid32, wblk, 0, stream>>>(bufX, rowstart, csr, dinv, bufY, stats2, N);

  // ---- layer 3 (BN2+ReLU+dropout fused) + log_softmax ----
  // 48-row padded W3 tile computes zeros into pad cols 40..47 of the 64-ch row
  k_gemm_mfma<3, 2, 0><<<ggrid, 256, 0, stream>>>(bufY, WT3, dinv,
      stats2, g2, be2, mask2, nullptr, 0u, 0u, 0,
      invN, bufX, N, 64);
  k_agg40lsm<<<wgrid16, wblk, 0, stream>>>(bufX, rowstart, csr, dinv, b3, out, N);
}